// Round 1
// 2783.382 us; speedup vs baseline: 1.1832x; 1.1832x over previous
//
#include <hip/hip_runtime.h>
#include <hip/hip_bf16.h>

// Problem sizes (fixed by reference)
#define NP_ 50000
#define NA_ 100000
#define EC_ 300000
#define EW_ 500000
#define PD_ 768
#define AD_ 128
#define ED_ 768
#define HD_ 64

// ---------------------------------------------------------------------------
// K1/K2: out[row][n] = relu( sum_k X[row][k] * W[k][n] + b[n] ), N=64
// 16 rows per block, 256 threads (4 waves x 4 rows each), X rows staged in LDS
// ---------------------------------------------------------------------------
template <int KK>
__global__ __launch_bounds__(256) void proj_relu_kernel(
    const float* __restrict__ X, const float* __restrict__ W,
    const float* __restrict__ b, float* __restrict__ out) {
  __shared__ float xs[16][KK];
  const int t = threadIdx.x;
  const size_t row_base = (size_t)blockIdx.x * 16;

  const float4* s4 = (const float4*)(X + row_base * KK);
  float4* d4 = (float4*)&xs[0][0];
  const int nvec = 16 * KK / 4;
  for (int vI = t; vI < nvec; vI += 256) d4[vI] = s4[vI];
  __syncthreads();

  const int n = t & 63, w = t >> 6;
  float acc[4] = {0.f, 0.f, 0.f, 0.f};
  for (int k = 0; k < KK; k += 4) {
    const float w0 = W[(k + 0) * 64 + n];
    const float w1 = W[(k + 1) * 64 + n];
    const float w2 = W[(k + 2) * 64 + n];
    const float w3 = W[(k + 3) * 64 + n];
#pragma unroll
    for (int i = 0; i < 4; ++i) {
      const float4 x4 = *(const float4*)&xs[w * 4 + i][k];
      acc[i] += x4.x * w0 + x4.y * w1 + x4.z * w2 + x4.w * w3;
    }
  }
  const float bn = b[n];
#pragma unroll
  for (int i = 0; i < 4; ++i) {
    const size_t row = row_base + w * 4 + i;
    out[row * 64 + n] = fmaxf(acc[i] + bn, 0.f);
  }
}

// ---------------------------------------------------------------------------
// K4: scatter-sum xa rows over writes edges + degree count
// one lane per (edge, col); 500000*64/256 = 125000 blocks exactly
// ---------------------------------------------------------------------------
__global__ __launch_bounds__(256) void sage_scatter_kernel(
    const float* __restrict__ xa, const int* __restrict__ wsrc,
    const int* __restrict__ wdst, float* __restrict__ agg,
    float* __restrict__ deg) {
  const int tid = blockIdx.x * 256 + threadIdx.x;
  const int e = tid >> 6, n = tid & 63;
  const int s = wsrc[e], d = wdst[e];
  atomicAdd(&agg[(size_t)d * 64 + n], xa[(size_t)s * 64 + n]);
  if (n == 0) atomicAdd(&deg[d], 1.0f);
}

// ---------------------------------------------------------------------------
// K56: per paper row: h_sage = mean_nb@Wl + bl + xp@Wr ; q,k,v = xp@W{q,k,v}+b
// 16 rows per block
// ---------------------------------------------------------------------------
__global__ __launch_bounds__(256) void sage_qkv_kernel(
    const float* __restrict__ xp, const float* __restrict__ agg,
    const float* __restrict__ deg, const float* __restrict__ Wl,
    const float* __restrict__ bl, const float* __restrict__ Wr,
    const float* __restrict__ Wq, const float* __restrict__ bq,
    const float* __restrict__ Wk, const float* __restrict__ bk,
    const float* __restrict__ Wv, const float* __restrict__ bv,
    float* __restrict__ h_sage, float* __restrict__ qo,
    float* __restrict__ ko, float* __restrict__ vo) {
  __shared__ float xs[16][64];
  __shared__ float ms[16][64];
  const int t = threadIdx.x;
  const size_t row_base = (size_t)blockIdx.x * 16;
  {
    const float4* a4 = (const float4*)(agg + row_base * 64);
    const float4* x4 = (const float4*)(xp + row_base * 64);
    const int i = t >> 4;  // local row of this float4 (t*4/64)
    const float rd = 1.0f / fmaxf(deg[row_base + i], 1.0f);
    float4 av = a4[t];
    av.x *= rd; av.y *= rd; av.z *= rd; av.w *= rd;
    ((float4*)&ms[0][0])[t] = av;
    ((float4*)&xs[0][0])[t] = x4[t];
  }
  __syncthreads();
  const int n = t & 63, w = t >> 6;
  float hs[4] = {0, 0, 0, 0}, aq[4] = {0, 0, 0, 0};
  float ak[4] = {0, 0, 0, 0}, av_[4] = {0, 0, 0, 0};
  for (int kk = 0; kk < 64; ++kk) {
    const float wl = Wl[kk * 64 + n];
    const float wr = Wr[kk * 64 + n];
    const float wq = Wq[kk * 64 + n];
    const float wk = Wk[kk * 64 + n];
    const float wv = Wv[kk * 64 + n];
#pragma unroll
    for (int i = 0; i < 4; ++i) {
      const float xv = xs[w * 4 + i][kk];
      const float mv = ms[w * 4 + i][kk];
      hs[i] += mv * wl + xv * wr;
      aq[i] += xv * wq;
      ak[i] += xv * wk;
      av_[i] += xv * wv;
    }
  }
  const float bln = bl[n], bqn = bq[n], bkn = bk[n], bvn = bv[n];
#pragma unroll
  for (int i = 0; i < 4; ++i) {
    const size_t row = row_base + w * 4 + i;
    h_sage[row * 64 + n] = hs[i] + bln;
    qo[row * 64 + n] = aq[i] + bqn;
    ko[row * 64 + n] = ak[i] + bkn;
    vo[row * 64 + n] = av_[i] + bvn;
  }
}

// ---------------------------------------------------------------------------
// K7: edge kernel. 16 edges/block, 4 waves. Chunked attr staging (3 x K=256)
// so LDS = 16KB stage + 8KB partials = 24KB -> ~6 blocks/CU (vs 64KB -> 2).
//   e_feat partial split: wave w owns edges [(w>>1)*8, +8) x K-half (w&1).
//     We is read 2x per block (L2-resident, cheap) instead of 1x, in exchange
//     for halving the partial buffer and register accumulators.
//   head_attr partial folded into the same streamed pass (attr read once).
// ---------------------------------------------------------------------------
__global__ __launch_bounds__(256, 6) void edge_kernel(
    const float* __restrict__ attr, const float* __restrict__ We,
    const float* __restrict__ be, const float* __restrict__ q,
    const float* __restrict__ kmat, const int* __restrict__ src,
    const int* __restrict__ dst, const float* __restrict__ dt,
    const float* __restrict__ lam_p, const float* __restrict__ Wh,
    float* __restrict__ ex_buf, float* __restrict__ denom,
    float* __restrict__ head_attr) {
  __shared__ float as_[16][256];   // 16 KB attr chunk
  __shared__ float ps[2][16][64];  // 8 KB e_feat partials
  const int t = threadIdx.x;
  const int n = t & 63, w = t >> 6;
  const size_t e_base = (size_t)blockIdx.x * 16;

  const int eg8 = (w >> 1) * 8;  // this wave's 8-edge group for the GEMM
  const int kh = (w & 1) * 128;  // this wave's K-half within each chunk
  const float* WhA = Wh + 128 * 3;

  float acc[8];
#pragma unroll
  for (int i = 0; i < 8; ++i) acc[i] = 0.f;
  float hp[4][3];
#pragma unroll
  for (int i = 0; i < 4; ++i) hp[i][0] = hp[i][1] = hp[i][2] = 0.f;

  for (int c = 0; c < 3; ++c) {
    const int ck0 = c << 8;
    if (c) __syncthreads();  // protect as_ from overwrite while still read
    // stage 16 rows x 256 cols (coalesced: 1024B contiguous per row)
    for (int vI = t; vI < 1024; vI += 256) {
      const int r = vI >> 6, c4 = vI & 63;
      ((float4*)&as_[r][0])[c4] =
          ((const float4*)(attr + (e_base + r) * 768 + ck0))[c4];
    }
    __syncthreads();

    // e_feat partial: 8 edges, this wave's K-half of the chunk
    for (int kk = kh; kk < kh + 128; kk += 4) {
      const int gk = ck0 + kk;
      const float w0 = We[(gk + 0) * 64 + n];
      const float w1 = We[(gk + 1) * 64 + n];
      const float w2 = We[(gk + 2) * 64 + n];
      const float w3 = We[(gk + 3) * 64 + n];
#pragma unroll
      for (int i = 0; i < 8; ++i) {
        const float4 a4 = *(const float4*)&as_[eg8 + i][kk];  // broadcast
        acc[i] += a4.x * w0 + a4.y * w1 + a4.z * w2 + a4.w * w3;
      }
    }

    // head_attr partial: wave w owns edges 4w..4w+3; lane n covers k==n mod 64
#pragma unroll
    for (int kt = 0; kt < 4; ++kt) {
      const int k = n + kt * 64;
      const float* whr = WhA + (size_t)(ck0 + k) * 3;
      const float wh0 = whr[0], wh1 = whr[1], wh2 = whr[2];
#pragma unroll
      for (int i = 0; i < 4; ++i) {
        const float av = as_[4 * w + i][k];  // stride-1 across lanes: no conflict
        hp[i][0] += av * wh0;
        hp[i][1] += av * wh1;
        hp[i][2] += av * wh2;
      }
    }
  }

  // publish e_feat partials (disjoint slices; no sync needed before write)
#pragma unroll
  for (int i = 0; i < 8; ++i) ps[w & 1][eg8 + i][n] = acc[i];
  __syncthreads();

  // combine partials -> e_feat, then alpha for this wave's 4 edges
  const float lam = fabsf(lam_p[0]);
#pragma unroll
  for (int i = 0; i < 4; ++i) {
    const int el = 4 * w + i;
    const size_t eg = e_base + el;
    const float ef = ps[0][el][n] + ps[1][el][n] + be[n];
    const int sp = src[eg], dp = dst[eg];
    float tv = q[(size_t)dp * 64 + n] * kmat[(size_t)sp * 64 + n] * ef;
#pragma unroll
    for (int off = 32; off; off >>= 1) tv += __shfl_xor(tv, off);
    const float alpha = tv * 0.125f * expf(-lam * dt[eg]);
    const float exv = expf(alpha);
    if (n == 0) {
      ex_buf[eg] = exv;
      atomicAdd(&denom[dp], exv);
    }
  }

  // head_attr final: reduce register partials
#pragma unroll
  for (int i = 0; i < 4; ++i) {
    const size_t eg = e_base + 4 * w + i;
#pragma unroll
    for (int j = 0; j < 3; ++j) {
      float p = hp[i][j];
#pragma unroll
      for (int off = 32; off; off >>= 1) p += __shfl_xor(p, off);
      if (n == 0) head_attr[eg * 3 + j] = p + dt[eg] * Wh[896 * 3 + j];
    }
  }
}

// ---------------------------------------------------------------------------
// K8: normalize alpha, write alpha output, scatter-add v[src]*alpha into h_gat
// one lane per (edge, col); 300000*64/256 = 75000 blocks exactly
// ---------------------------------------------------------------------------
__global__ __launch_bounds__(256) void gat_scatter_kernel(
    const float* __restrict__ v, const int* __restrict__ src,
    const int* __restrict__ dst, const float* __restrict__ ex_buf,
    const float* __restrict__ denom, float* __restrict__ h_gat,
    float* __restrict__ alpha_out) {
  const int tid = blockIdx.x * 256 + threadIdx.x;
  const int e = tid >> 6, n = tid & 63;
  const int sp = src[e], dp = dst[e];
  const float wgt = ex_buf[e] / (denom[dp] + 1e-16f);
  atomicAdd(&h_gat[(size_t)dp * 64 + n], wgt * v[(size_t)sp * 64 + n]);
  if (n == 0) alpha_out[e] = wgt;
}

// ---------------------------------------------------------------------------
// K9/10a: h_papers = relu(h_sage + h_gat) folded straight into head proj:
//   c_src[p][j] = h_papers[p] . W_head[0:64, j]
//   c_dst[p][j] = h_papers[p] . W_head[64:128, j]
// wave per paper; h_papers never materialized
// ---------------------------------------------------------------------------
__global__ __launch_bounds__(256) void paper_head_kernel(
    const float* __restrict__ h_sage, const float* __restrict__ h_gat,
    const float* __restrict__ Wh, float* __restrict__ c_src,
    float* __restrict__ c_dst) {
  const int t = threadIdx.x, n = t & 63, w = t >> 6;
  const size_t p = (size_t)blockIdx.x * 4 + w;
  const float val = fmaxf(h_sage[p * 64 + n] + h_gat[p * 64 + n], 0.f);
  float r[6];
#pragma unroll
  for (int j = 0; j < 3; ++j) {
    r[j] = val * Wh[n * 3 + j];
    r[3 + j] = val * Wh[(64 + n) * 3 + j];
  }
#pragma unroll
  for (int j = 0; j < 6; ++j) {
#pragma unroll
    for (int off = 32; off; off >>= 1) r[j] += __shfl_xor(r[j], off);
  }
  if (n == 0) {
#pragma unroll
    for (int j = 0; j < 3; ++j) {
      c_src[p * 3 + j] = r[j];
      c_dst[p * 3 + j] = r[3 + j];
    }
  }
}

// ---------------------------------------------------------------------------
// K10b: logits[e][j] = c_src[src][j] + c_dst[dst][j] + head_attr[e][j] + b[j]
// ---------------------------------------------------------------------------
__global__ __launch_bounds__(256) void edge_head_kernel(
    const int* __restrict__ src, const int* __restrict__ dst,
    const float* __restrict__ c_src, const float* __restrict__ c_dst,
    const float* __restrict__ head_attr, const float* __restrict__ bh,
    float* __restrict__ logits) {
  const int e = blockIdx.x * 256 + threadIdx.x;
  if (e >= EC_) return;
  const int sp = src[e], dp = dst[e];
#pragma unroll
  for (int j = 0; j < 3; ++j) {
    logits[(size_t)e * 3 + j] = c_src[(size_t)sp * 3 + j] +
                                c_dst[(size_t)dp * 3 + j] +
                                head_attr[(size_t)e * 3 + j] + bh[j];
  }
}

// ---------------------------------------------------------------------------
extern "C" void kernel_launch(void* const* d_in, const int* in_sizes, int n_in,
                              void* d_out, int out_size, void* d_ws,
                              size_t ws_size, hipStream_t stream) {
  const float* x_paper = (const float*)d_in[0];
  const float* x_author = (const float*)d_in[1];
  const int* cei = (const int*)d_in[2];
  const int* wsrc = (const int*)d_in[3];
  const int* wdst = (const int*)d_in[4];
  const float* attr = (const float*)d_in[5];
  const float* dt = (const float*)d_in[6];
  const float* W_pp = (const float*)d_in[7];
  const float* b_pp = (const float*)d_in[8];
  const float* W_ap = (const float*)d_in[9];
  const float* b_ap = (const float*)d_in[10];
  const float* Wq = (const float*)d_in[11];
  const float* bq = (const float*)d_in[12];
  const float* Wk = (const float*)d_in[13];
  const float* bk = (const float*)d_in[14];
  const float* Wv = (const float*)d_in[15];
  const float* bv = (const float*)d_in[16];
  const float* We = (const float*)d_in[17];
  const float* be = (const float*)d_in[18];
  const float* lam = (const float*)d_in[19];
  const float* sage_Wl = (const float*)d_in[20];
  const float* sage_bl = (const float*)d_in[21];
  const float* sage_Wr = (const float*)d_in[22];
  const float* W_head = (const float*)d_in[23];
  const float* b_head = (const float*)d_in[24];

  const int* src = cei;        // row 0
  const int* dstp = cei + EC_; // row 1

  // workspace layout (floats)
  float* ws = (float*)d_ws;
  float* xa = ws;                        // 6,400,000
  float* xp = xa + (size_t)NA_ * 64;     // 3,200,000
  float* agg = xp + (size_t)NP_ * 64;    // 3,200,000 (zeroed)
  float* deg = agg + (size_t)NP_ * 64;   // 50,000    (zeroed)
  float* denom = deg + NP_;              // 50,000    (zeroed)
  float* h_gat = denom + NP_;            // 3,200,000 (zeroed)
  float* h_sage = h_gat + (size_t)NP_ * 64;
  float* q = h_sage + (size_t)NP_ * 64;
  float* k = q + (size_t)NP_ * 64;
  float* v = k + (size_t)NP_ * 64;
  float* ex_buf = v + (size_t)NP_ * 64;      // 300,000
  float* head_attr = ex_buf + EC_;           // 900,000
  float* c_src = head_attr + (size_t)EC_ * 3; // 150,000
  float* c_dst = c_src + (size_t)NP_ * 3;     // 150,000

  // zero the accumulated regions (agg, deg, denom, h_gat are contiguous)
  hipMemsetAsync(agg, 0, (size_t)(NP_ * 64 + NP_ + NP_ + NP_ * 64) * sizeof(float), stream);

  float* logits = (float*)d_out;            // 900,000
  float* alpha_out = logits + (size_t)EC_ * 3; // 300,000

  // K1: author projection (100000 rows, K=128)
  proj_relu_kernel<128><<<NA_ / 16, 256, 0, stream>>>(x_author, W_ap, b_ap, xa);
  // K4: scatter writes
  sage_scatter_kernel<<<EW_ * 64 / 256, 256, 0, stream>>>(xa, wsrc, wdst, agg, deg);
  // K2: paper projection (50000 rows, K=768)
  proj_relu_kernel<768><<<NP_ / 16, 256, 0, stream>>>(x_paper, W_pp, b_pp, xp);
  // K56: sage combine + q,k,v
  sage_qkv_kernel<<<NP_ / 16, 256, 0, stream>>>(xp, agg, deg, sage_Wl, sage_bl,
                                                sage_Wr, Wq, bq, Wk, bk, Wv, bv,
                                                h_sage, q, k, v);
  // K7: edge kernel (e_feat + alpha numerator + denom + head_attr)
  edge_kernel<<<EC_ / 16, 256, 0, stream>>>(attr, We, be, q, k, src, dstp, dt,
                                            lam, W_head, ex_buf, denom, head_attr);
  // K8: normalize + scatter into h_gat, write alpha output
  gat_scatter_kernel<<<EC_ * 64 / 256, 256, 0, stream>>>(v, src, dstp, ex_buf,
                                                         denom, h_gat, alpha_out);
  // K9/10a: relu + per-paper head contributions
  paper_head_kernel<<<NP_ / 4, 256, 0, stream>>>(h_sage, h_gat, W_head, c_src, c_dst);
  // K10b: final logits
  edge_head_kernel<<<(EC_ + 255) / 256, 256, 0, stream>>>(src, dstp, c_src, c_dst,
                                                          head_attr, b_head, logits);
}